// Round 1
// baseline (96.296 us; speedup 1.0000x reference)
//
#include <hip/hip_runtime.h>
#include <math.h>

#define L_DIM 4096
#define N_DIM 2048
#define INV_W (1.0f / 640.0f)
#define INV_H (1.0f / 480.0f)
#define TWO_PI_3 2.0943951023931953  // 2*pi/3

__global__ __launch_bounds__(256) void distopt_kernel(
    const float* __restrict__ inp,      // (L, N, 2) f32
    const float* __restrict__ center,   // (2,) f32
    const float* __restrict__ alpha_p,  // (1,) f32
    float* __restrict__ out)            // (L,) f32
{
    const int l = blockIdx.x;
    const int t = threadIdx.x;
    const float cx = center[0];
    const float cy = center[1];
    const float alpha = alpha_p[0];

    // Row l: 2048 points * 2 floats = 4096 floats = 1024 float4
    const float4* row = (const float4*)(inp + (size_t)l * (N_DIM * 2));

    float4 v[4];
#pragma unroll
    for (int i = 0; i < 4; ++i) v[i] = row[t + 256 * i];

    double sxx = 0.0, sxy = 0.0, syy = 0.0, sx = 0.0, sy = 0.0;
#pragma unroll
    for (int i = 0; i < 4; ++i) {
        float pxs[2] = { v[i].x, v[i].z };
        float pys[2] = { v[i].y, v[i].w };
#pragma unroll
        for (int j = 0; j < 2; ++j) {
            // und = (1 + alpha*r2)*shifted + center   (all fp32, matches ref)
            float shx = pxs[j] * INV_W - cx;
            float shy = pys[j] * INV_H - cy;
            float r2 = shx * shx + shy * shy;
            float f = 1.0f + alpha * r2;
            double ux = (double)(f * shx + cx);
            double uy = (double)(f * shy + cy);
            sxx += ux * ux;
            sxy += ux * uy;
            syy += uy * uy;
            sx  += ux;
            sy  += uy;
        }
    }

    // wave (64-lane) shuffle reduction
#pragma unroll
    for (int off = 32; off > 0; off >>= 1) {
        sxx += __shfl_down(sxx, off);
        sxy += __shfl_down(sxy, off);
        syy += __shfl_down(syy, off);
        sx  += __shfl_down(sx,  off);
        sy  += __shfl_down(sy,  off);
    }

    __shared__ double red[4][5];
    const int wave = t >> 6;
    if ((t & 63) == 0) {
        red[wave][0] = sxx; red[wave][1] = sxy; red[wave][2] = syy;
        red[wave][3] = sx;  red[wave][4] = sy;
    }
    __syncthreads();

    if (t == 0) {
        double Sxx = 0, Sxy = 0, Syy = 0, Sx = 0, Sy = 0;
#pragma unroll
        for (int w = 0; w < 4; ++w) {
            Sxx += red[w][0]; Sxy += red[w][1]; Syy += red[w][2];
            Sx  += red[w][3]; Sy  += red[w][4];
        }

        // M = sum of (x, y, -1)^T (x, y, -1)
        const double m00 = Sxx, m01 = Sxy, m02 = -Sx;
        const double m11 = Syy, m12 = -Sy;
        const double m22 = (double)N_DIM;

        // Smallest eigenvalue via trigonometric method (fp64)
        double q  = (m00 + m11 + m22) * (1.0 / 3.0);
        double p1 = m01 * m01 + m02 * m02 + m12 * m12;
        double d0 = m00 - q, d1 = m11 - q, d2 = m22 - q;
        double p2 = d0 * d0 + d1 * d1 + d2 * d2 + 2.0 * p1;
        double p  = sqrt(p2 * (1.0 / 6.0));
        double ip = 1.0 / p;
        double b00 = d0 * ip, b11 = d1 * ip, b22 = d2 * ip;
        double b01 = m01 * ip, b02 = m02 * ip, b12 = m12 * ip;
        double detB = b00 * (b11 * b22 - b12 * b12)
                    - b01 * (b01 * b22 - b12 * b02)
                    + b02 * (b01 * b12 - b11 * b02);
        double r = detB * 0.5;
        r = fmin(1.0, fmax(-1.0, r));
        double phi = acos(r) * (1.0 / 3.0);
        double lam = q + 2.0 * p * cos(phi + TWO_PI_3);  // smallest eigenvalue

        // Eigenvector: max-norm cross product of rows of (M - lam I)
        double a00 = m00 - lam, a11 = m11 - lam, a22 = m22 - lam;
        // rows: r0=(a00,m01,m02) r1=(m01,a11,m12) r2=(m02,m12,a22)
        double c0x = m01 * m12 - m02 * a11;
        double c0y = m02 * m01 - a00 * m12;
        double c0z = a00 * a11 - m01 * m01;
        double c1x = m01 * a22 - m02 * m12;
        double c1y = m02 * m02 - a00 * a22;
        double c1z = a00 * m12 - m01 * m02;
        double c2x = a11 * a22 - m12 * m12;
        double c2y = m12 * m02 - m01 * a22;
        double c2z = m01 * m12 - a11 * m02;
        double n0 = c0x * c0x + c0y * c0y + c0z * c0z;
        double n1 = c1x * c1x + c1y * c1y + c1z * c1z;
        double n2 = c2x * c2x + c2y * c2y + c2z * c2z;

        double zx = c0x, zy = c0y, nn = n0;
        if (n1 > nn) { zx = c1x; zy = c1y; nn = n1; }
        if (n2 > nn) { zx = c2x; zy = c2y; nn = n2; }

        // output = lam * |z|^2 / (z0^2 + z1^2)
        out[l] = (float)(lam * nn / (zx * zx + zy * zy));
    }
}

extern "C" void kernel_launch(void* const* d_in, const int* in_sizes, int n_in,
                              void* d_out, int out_size, void* d_ws, size_t ws_size,
                              hipStream_t stream) {
    const float* inp    = (const float*)d_in[0];
    const float* center = (const float*)d_in[1];
    const float* alpha  = (const float*)d_in[2];
    float* out = (float*)d_out;
    (void)in_sizes; (void)n_in; (void)d_ws; (void)ws_size;

    dim3 grid(out_size);   // L = 4096 blocks, one per output element
    dim3 block(256);
    hipLaunchKernelGGL(distopt_kernel, grid, block, 0, stream,
                       inp, center, alpha, out);
}

// Round 2
// 95.090 us; speedup vs baseline: 1.0127x; 1.0127x over previous
//
#include <hip/hip_runtime.h>
#include <math.h>

#define L_DIM 4096
#define N_DIM 2048
#define INV_W (1.0f / 640.0f)
#define INV_H (1.0f / 480.0f)
#define TWO_PI_3 2.0943951023931953  // 2*pi/3

// One 64-lane wave per row l. 256 threads/block = 4 rows/block.
// Per lane: 16 float4 = 32 points; fp64 moment accumulation in-registers;
// single-wave shuffle reduction (no LDS, no __syncthreads).
__global__ __launch_bounds__(256) void distopt_kernel(
    const float* __restrict__ inp,      // (L, N, 2) f32
    const float* __restrict__ center,   // (2,) f32
    const float* __restrict__ alpha_p,  // (1,) f32
    float* __restrict__ out)            // (L,) f32
{
    const int wave = threadIdx.x >> 6;
    const int lane = threadIdx.x & 63;
    const int l = blockIdx.x * 4 + wave;
    if (l >= L_DIM) return;

    const float cx = center[0];
    const float cy = center[1];
    const float alpha = alpha_p[0];

    // Row l: 2048 points * 2 floats = 4096 floats = 1024 float4
    const float4* row = (const float4*)(inp + (size_t)l * (N_DIM * 2));

    // Load all 16 float4 up-front for maximum memory-level parallelism.
    float4 v[16];
#pragma unroll
    for (int k = 0; k < 16; ++k) v[k] = row[lane + 64 * k];

    double sxx = 0.0, sxy = 0.0, syy = 0.0, sx = 0.0, sy = 0.0;
#pragma unroll
    for (int k = 0; k < 16; ++k) {
        float pxs[2] = { v[k].x, v[k].z };
        float pys[2] = { v[k].y, v[k].w };
#pragma unroll
        for (int j = 0; j < 2; ++j) {
            // und = (1 + alpha*r2)*shifted + center   (fp32, matches ref fwd)
            float shx = pxs[j] * INV_W - cx;
            float shy = pys[j] * INV_H - cy;
            float r2 = shx * shx + shy * shy;
            float f = 1.0f + alpha * r2;
            double ux = (double)(f * shx + cx);
            double uy = (double)(f * shy + cy);
            sxx += ux * ux;
            sxy += ux * uy;
            syy += uy * uy;
            sx  += ux;
            sy  += uy;
        }
    }

    // Single-wave 64-lane shuffle reduction (5 fp64 vars, 6 levels)
#pragma unroll
    for (int off = 32; off > 0; off >>= 1) {
        sxx += __shfl_down(sxx, off);
        sxy += __shfl_down(sxy, off);
        syy += __shfl_down(syy, off);
        sx  += __shfl_down(sx,  off);
        sy  += __shfl_down(sy,  off);
    }

    if (lane == 0) {
        // M = sum of (x, y, -1)^T (x, y, -1)
        const double m00 = sxx, m01 = sxy, m02 = -sx;
        const double m11 = syy, m12 = -sy;
        const double m22 = (double)N_DIM;

        // Smallest eigenvalue via trigonometric method (fp64)
        double q  = (m00 + m11 + m22) * (1.0 / 3.0);
        double p1 = m01 * m01 + m02 * m02 + m12 * m12;
        double d0 = m00 - q, d1 = m11 - q, d2 = m22 - q;
        double p2 = d0 * d0 + d1 * d1 + d2 * d2 + 2.0 * p1;
        double p  = sqrt(p2 * (1.0 / 6.0));
        double ip = 1.0 / p;
        double b00 = d0 * ip, b11 = d1 * ip, b22 = d2 * ip;
        double b01 = m01 * ip, b02 = m02 * ip, b12 = m12 * ip;
        double detB = b00 * (b11 * b22 - b12 * b12)
                    - b01 * (b01 * b22 - b12 * b02)
                    + b02 * (b01 * b12 - b11 * b02);
        double r = detB * 0.5;
        r = fmin(1.0, fmax(-1.0, r));
        double phi = acos(r) * (1.0 / 3.0);
        double lam = q + 2.0 * p * cos(phi + TWO_PI_3);  // smallest eigenvalue

        // Eigenvector: max-norm cross product of rows of (M - lam I)
        double a00 = m00 - lam, a11 = m11 - lam, a22 = m22 - lam;
        double c0x = m01 * m12 - m02 * a11;
        double c0y = m02 * m01 - a00 * m12;
        double c0z = a00 * a11 - m01 * m01;
        double c1x = m01 * a22 - m02 * m12;
        double c1y = m02 * m02 - a00 * a22;
        double c1z = a00 * m12 - m01 * m02;
        double c2x = a11 * a22 - m12 * m12;
        double c2y = m12 * m02 - m01 * a22;
        double c2z = m01 * m12 - a11 * m02;
        double n0 = c0x * c0x + c0y * c0y + c0z * c0z;
        double n1 = c1x * c1x + c1y * c1y + c1z * c1z;
        double n2 = c2x * c2x + c2y * c2y + c2z * c2z;

        double zx = c0x, zy = c0y, nn = n0;
        if (n1 > nn) { zx = c1x; zy = c1y; nn = n1; }
        if (n2 > nn) { zx = c2x; zy = c2y; nn = n2; }

        // output = lam * |z|^2 / (z0^2 + z1^2)
        out[l] = (float)(lam * nn / (zx * zx + zy * zy));
    }
}

extern "C" void kernel_launch(void* const* d_in, const int* in_sizes, int n_in,
                              void* d_out, int out_size, void* d_ws, size_t ws_size,
                              hipStream_t stream) {
    const float* inp    = (const float*)d_in[0];
    const float* center = (const float*)d_in[1];
    const float* alpha  = (const float*)d_in[2];
    float* out = (float*)d_out;
    (void)in_sizes; (void)n_in; (void)d_ws; (void)ws_size;

    dim3 grid((out_size + 3) / 4);  // 4 rows (waves) per 256-thread block
    dim3 block(256);
    hipLaunchKernelGGL(distopt_kernel, grid, block, 0, stream,
                       inp, center, alpha, out);
}